// Round 1
// baseline (49.012 us; speedup 1.0000x reference)
//
#include <hip/hip_runtime.h>
#include <hip/hip_bf16.h>

// QuantizedLinear: out[t][o] = scale[o] * (sum_k x[t][k]*q[o][k] - zp[o]*sum_k x[t][k]) + bias[o]
// T=8, K=4096, OUT=11008. Weights are int32 (int8-valued): 180 MB -> memory-bound.
//
// Structure: block = 256 threads = 4 waves.
//   wave w: local channel-group gl = w>>1 (8 channels), K-half kh = w&1 (2048 k's).
//   Each lane: float4 x-loads (reused across 8 channels) + int4 q-loads,
//   64 fp32 accumulators (8 tokens x 8 channels).
//   End: halving-butterfly reduce (63 shfl+add) -> lane l holds (t=l>>3, c=l&7).
//   K-halves combined via 512B LDS; kh==0 wave applies scale/zp/bias and stores.
// Grid: OUT/16 = 688 blocks (each block covers 16 channels, all 8 tokens).

constexpr int T_TOK = 8;
constexpr int K_IN  = 4096;
constexpr int N_OUT = 11008;
constexpr int KHALF = K_IN / 2;          // 2048
constexpr int ITERS = KHALF / (64 * 4);  // 8

__global__ __launch_bounds__(256) void qlin_kernel(
    const float* __restrict__ x,
    const int*   __restrict__ q,
    const float* __restrict__ scale,
    const int*   __restrict__ zp,
    const float* __restrict__ bias,
    float*       __restrict__ out)
{
    __shared__ float partial[2][64];

    const int tid  = threadIdx.x;
    const int lane = tid & 63;
    const int w    = tid >> 6;        // wave in block: 0..3
    const int gl   = w >> 1;          // local channel group: 0..1
    const int kh   = w & 1;           // k-half: 0..1
    const int obase = blockIdx.x * 16 + gl * 8;
    const int kbase = kh * KHALF;

    float acc[64];
    #pragma unroll
    for (int i = 0; i < 64; ++i) acc[i] = 0.0f;
    float xs[8];
    #pragma unroll
    for (int t = 0; t < 8; ++t) xs[t] = 0.0f;

    for (int it = 0; it < ITERS; ++it) {
        const int k0 = kbase + it * 256 + lane * 4;

        float4 xv[8];
        #pragma unroll
        for (int t = 0; t < 8; ++t)
            xv[t] = *reinterpret_cast<const float4*>(&x[t * K_IN + k0]);

        int4 qv[8];
        #pragma unroll
        for (int c = 0; c < 8; ++c)
            qv[c] = *reinterpret_cast<const int4*>(&q[(obase + c) * K_IN + k0]);

        #pragma unroll
        for (int c = 0; c < 8; ++c) {
            const float q0 = (float)qv[c].x;
            const float q1 = (float)qv[c].y;
            const float q2 = (float)qv[c].z;
            const float q3 = (float)qv[c].w;
            #pragma unroll
            for (int t = 0; t < 8; ++t) {
                acc[t * 8 + c] += xv[t].x * q0 + xv[t].y * q1
                                + xv[t].z * q2 + xv[t].w * q3;
            }
        }
        #pragma unroll
        for (int t = 0; t < 8; ++t)
            xs[t] += xv[t].x + xv[t].y + xv[t].z + xv[t].w;
    }

    // Halving butterfly: 64 values x 64 lanes -> lane l holds fully-reduced
    // value j=l (t = l>>3, c = l&7). Total 63 shfl + 63 add.
    #pragma unroll
    for (int s = 0; s < 6; ++s) {
        const int m    = 32 >> s;
        const int half = 32 >> s;
        const bool hi  = (lane & m) != 0;
        #pragma unroll
        for (int i = 0; i < half; ++i) {
            const float a = acc[i];
            const float b = acc[i + half];
            const float send = hi ? a : b;
            const float recv = __shfl_xor(send, m, 64);
            acc[i] = (hi ? b : a) + recv;
        }
    }

    // Full butterfly for per-token x sums (every lane gets all 8 totals).
    #pragma unroll
    for (int m = 1; m <= 32; m <<= 1) {
        #pragma unroll
        for (int t = 0; t < 8; ++t)
            xs[t] += __shfl_xor(xs[t], m, 64);
    }

    const int t = lane >> 3;
    const int c = lane & 7;
    const int o = obase + c;
    const float v = acc[0] - (float)zp[o] * xs[t];

    if (kh == 1)
        partial[gl][lane] = v;
    __syncthreads();
    if (kh == 0) {
        const float r = scale[o] * (v + partial[gl][lane]) + bias[o];
        out[t * N_OUT + o] = r;
    }
}

extern "C" void kernel_launch(void* const* d_in, const int* in_sizes, int n_in,
                              void* d_out, int out_size, void* d_ws, size_t ws_size,
                              hipStream_t stream) {
    const float* x     = (const float*)d_in[0];
    const int*   q     = (const int*)  d_in[1];
    const float* scale = (const float*)d_in[2];
    const int*   zp    = (const int*)  d_in[3];
    const float* bias  = (const float*)d_in[4];
    float* out = (float*)d_out;

    const int blocks = N_OUT / 16;  // 688
    qlin_kernel<<<blocks, 256, 0, stream>>>(x, q, scale, zp, bias, out);
}

// Round 2
// 43.300 us; speedup vs baseline: 1.1319x; 1.1319x over previous
//
#include <hip/hip_runtime.h>
#include <hip/hip_bf16.h>

// QuantizedLinear: out[t][o] = scale[o] * (sum_k x[t][k]*q[o][k] - zp[o]*sum_k x[t][k]) + bias[o]
// T=8, K=4096, OUT=11008. Weights int32 (int8-valued): 180.4 MB streamed once -> memory-bound.
// Roofline: 181 MB @ ~7 TB/s (measured fill BW) ~= 26 us.
//
// R2 structure (split-K=4 for 2x wave count vs R1):
//   block = 256 threads = 4 waves, all on the SAME 8 output channels.
//   wave w handles K-quarter w (1024 k's = 4 iters of 256 k).
//   Per iter per lane: 8 float4 x-loads (L2-resident, reused across 8 channels)
//                    + 8 int4 q-loads (HBM) -> 1:1 load ratio, 16B/lane each.
//   64 fp32 acc (8 tokens x 8 channels); halving butterfly (63 shfl+add)
//   leaves lane l = (t=l>>3, c=l&7); waves 1..3 spill to LDS, wave 0 combines,
//   applies scale/zp/bias, stores.
// Grid: 11008/8 = 1376 blocks -> 5504 waves = 5.4 waves/SIMD of work.

constexpr int K_IN  = 4096;
constexpr int N_OUT = 11008;
constexpr int KQ    = K_IN / 4;          // 1024 per wave
constexpr int ITERS = KQ / (64 * 4);     // 4

__global__ __launch_bounds__(256) void qlin_kernel(
    const float* __restrict__ x,
    const int*   __restrict__ q,
    const float* __restrict__ scale,
    const int*   __restrict__ zp,
    const float* __restrict__ bias,
    float*       __restrict__ out)
{
    __shared__ float partial[3][64];

    const int tid  = threadIdx.x;
    const int lane = tid & 63;
    const int w    = tid >> 6;        // wave in block: 0..3 = K-quarter
    const int obase = blockIdx.x * 8;
    const int kbase = w * KQ;

    float acc[64];
    #pragma unroll
    for (int i = 0; i < 64; ++i) acc[i] = 0.0f;
    float xs[8];
    #pragma unroll
    for (int t = 0; t < 8; ++t) xs[t] = 0.0f;

    #pragma unroll 2
    for (int it = 0; it < ITERS; ++it) {
        const int k0 = kbase + it * 256 + lane * 4;

        float4 xv[8];
        #pragma unroll
        for (int t = 0; t < 8; ++t)
            xv[t] = *reinterpret_cast<const float4*>(&x[t * K_IN + k0]);

        int4 qv[8];
        #pragma unroll
        for (int c = 0; c < 8; ++c)
            qv[c] = *reinterpret_cast<const int4*>(&q[(obase + c) * K_IN + k0]);

        #pragma unroll
        for (int c = 0; c < 8; ++c) {
            const float q0 = (float)qv[c].x;
            const float q1 = (float)qv[c].y;
            const float q2 = (float)qv[c].z;
            const float q3 = (float)qv[c].w;
            #pragma unroll
            for (int t = 0; t < 8; ++t) {
                acc[t * 8 + c] += xv[t].x * q0 + xv[t].y * q1
                                + xv[t].z * q2 + xv[t].w * q3;
            }
        }
        #pragma unroll
        for (int t = 0; t < 8; ++t)
            xs[t] += xv[t].x + xv[t].y + xv[t].z + xv[t].w;
    }

    // Halving butterfly: 64 partials x 64 lanes -> lane l holds value j=l
    // (t = l>>3, c = l&7), summed over this wave's K-quarter.
    #pragma unroll
    for (int s = 0; s < 6; ++s) {
        const int m    = 32 >> s;
        const int half = 32 >> s;
        const bool hi  = (lane & m) != 0;
        #pragma unroll
        for (int i = 0; i < half; ++i) {
            const float a = acc[i];
            const float b = acc[i + half];
            const float send = hi ? a : b;
            const float recv = __shfl_xor(send, m, 64);
            acc[i] = (hi ? b : a) + recv;
        }
    }

    // Full butterfly for per-token x partial sums (every lane gets this
    // wave's 8 K-quarter totals).
    #pragma unroll
    for (int m = 1; m <= 32; m <<= 1) {
        #pragma unroll
        for (int t = 0; t < 8; ++t)
            xs[t] += __shfl_xor(xs[t], m, 64);
    }

    const int t = lane >> 3;
    const int c = lane & 7;
    const int o = obase + c;
    const float v = acc[0] - (float)zp[o] * xs[t];   // zp correction per K-quarter

    if (w != 0)
        partial[w - 1][lane] = v;
    __syncthreads();
    if (w == 0) {
        const float total = v + partial[0][lane] + partial[1][lane] + partial[2][lane];
        out[t * N_OUT + o] = scale[o] * total + bias[o];
    }
}

extern "C" void kernel_launch(void* const* d_in, const int* in_sizes, int n_in,
                              void* d_out, int out_size, void* d_ws, size_t ws_size,
                              hipStream_t stream) {
    const float* x     = (const float*)d_in[0];
    const int*   q     = (const int*)  d_in[1];
    const float* scale = (const float*)d_in[2];
    const int*   zp    = (const int*)  d_in[3];
    const float* bias  = (const float*)d_in[4];
    float* out = (float*)d_out;

    const int blocks = N_OUT / 8;  // 1376
    qlin_kernel<<<blocks, 256, 0, stream>>>(x, q, scale, zp, bias, out);
}